// Round 1
// baseline (310.249 us; speedup 1.0000x reference)
//
#include <hip/hip_runtime.h>
#include <hip/hip_bf16.h>
#include <stdint.h>

// Problem: B=32768 queries, M=4096 memory rows, D=128.
//   logits = Q @ M^T ; attn = softmax(logits, axis=1) ; out = attn @ M
// Strategy: flash-attention fused kernel, bf16x3-split MFMA for QK^T
// (near-fp32 precision), plain-bf16 MFMA for PV, online softmax in
// log2 domain (log2e folded into Q). 32x32x16 MFMA, swapped QK so the
// softmax reduction axis is lane-local (q = lane&31 everywhere).

typedef float   f32x16 __attribute__((ext_vector_type(16)));
typedef short   bf16x8 __attribute__((ext_vector_type(8)));
typedef uint32_t u32;

#define D_DIM 128
#define M_ROWS 4096
#define MT_STEPS 128   // M_ROWS / 32

__device__ __forceinline__ uint16_t f32_to_bf16_rne(float x) {
    u32 u = __float_as_uint(x);
    u32 r = u + 0x7fffu + ((u >> 16) & 1u);
    return (uint16_t)(r >> 16);
}
__device__ __forceinline__ float bf16_to_f32(uint16_t h) {
    return __uint_as_float(((u32)h) << 16);
}

// ---------------------------------------------------------------------------
// Prep: rearrange memory into fragment-linear bf16 arrays in d_ws.
//   khi/klo: [mt][kk][lane][e]  (K operand of Sᵀ = K·Qᵀ, A-frag of 32x32x16)
//            element = memory[mt*32 + (lane&31)][kk*16 + (lane>>5)*8 + e]
//   vfr:     [mt][ks*4+dt][lane][e]  (Vᵀ operand of Oᵀ = Vᵀ·Pᵀ, A-frag)
//            element = memory[mt*32 + ks*16 + (lane>>5)*8 + e][dt*32 + (lane&31)]
// Each array: 128*8*64*8 = 524288 uint16 = 1 MB. Total ws use: 3 MB.
// ---------------------------------------------------------------------------
__global__ void prep_frags(const float* __restrict__ mem,
                           uint16_t* __restrict__ khi,
                           uint16_t* __restrict__ klo,
                           uint16_t* __restrict__ vfr) {
    int t = blockIdx.x * blockDim.x + threadIdx.x;  // 0..65535
    int lane = t & 63;
    int fi = t >> 6;                                // 0..1023
    {   // K fragment (hi/lo split)
        int kk = fi & 7, mt = fi >> 3;
        int m  = mt * 32 + (lane & 31);
        int d0 = kk * 16 + (lane >> 5) * 8;
        const float* src = mem + (size_t)m * D_DIM + d0;
        #pragma unroll
        for (int e = 0; e < 8; ++e) {
            float x = src[e];
            uint16_t hb = f32_to_bf16_rne(x);
            khi[(size_t)t * 8 + e] = hb;
            klo[(size_t)t * 8 + e] = f32_to_bf16_rne(x - bf16_to_f32(hb));
        }
    }
    {   // V fragment (plain bf16)
        int dt = fi & 3, ks = (fi >> 2) & 1, mt = fi >> 3;
        int d  = dt * 32 + (lane & 31);
        int m0 = mt * 32 + ks * 16 + (lane >> 5) * 8;
        #pragma unroll
        for (int e = 0; e < 8; ++e)
            vfr[(size_t)t * 8 + e] = f32_to_bf16_rne(mem[(size_t)(m0 + e) * D_DIM + d]);
    }
}

// ---------------------------------------------------------------------------
// Main fused kernel. Grid: 256 blocks x 256 threads = 1024 waves,
// each wave owns 32 q-rows (q = q0 + (lane&31)). No LDS.
// ---------------------------------------------------------------------------

#define LOADK(mt_, kh_, kl_) do {                                             \
    const uint16_t* bh_ = khi + (size_t)(mt_) * 4096 + lane * 8;              \
    const uint16_t* bl_ = klo + (size_t)(mt_) * 4096 + lane * 8;              \
    _Pragma("unroll")                                                         \
    for (int kk_ = 0; kk_ < 8; ++kk_) {                                       \
        kh_[kk_] = *(const bf16x8*)(bh_ + kk_ * 512);                         \
        kl_[kk_] = *(const bf16x8*)(bl_ + kk_ * 512);                         \
    }                                                                         \
} while (0)

#define STEP(mt_, kh_, kl_) do {                                              \
    /* V frags: issued now, consumed ~QK-phase later (latency hidden) */      \
    bf16x8 vf_[8];                                                            \
    { const uint16_t* bv_ = vfr + (size_t)(mt_) * 4096 + lane * 8;            \
      _Pragma("unroll")                                                       \
      for (int f_ = 0; f_ < 8; ++f_)                                          \
          vf_[f_] = *(const bf16x8*)(bv_ + f_ * 512); }                       \
    /* QK^T, bf16x3 split: 3 interleaved accumulator chains */                \
    f32x16 s0_, s1_, s2_;                                                     \
    _Pragma("unroll")                                                         \
    for (int i_ = 0; i_ < 16; ++i_) { s0_[i_] = 0.f; s1_[i_] = 0.f; s2_[i_] = 0.f; } \
    _Pragma("unroll")                                                         \
    for (int kk_ = 0; kk_ < 8; ++kk_) {                                       \
        s0_ = __builtin_amdgcn_mfma_f32_32x32x16_bf16(kh_[kk_], qhi[kk_], s0_, 0, 0, 0); \
        s1_ = __builtin_amdgcn_mfma_f32_32x32x16_bf16(kh_[kk_], qlo[kk_], s1_, 0, 0, 0); \
        s2_ = __builtin_amdgcn_mfma_f32_32x32x16_bf16(kl_[kk_], qhi[kk_], s2_, 0, 0, 0); \
    }                                                                         \
    f32x16 s_ = s0_ + s1_ + s2_;   /* Sᵀ[m][q], log2-domain logits */         \
    /* online softmax: q = lane&31, pair lane (lane^32) holds other 16 m */   \
    float tmax_ = s_[0];                                                      \
    _Pragma("unroll")                                                         \
    for (int r_ = 1; r_ < 16; ++r_) tmax_ = fmaxf(tmax_, s_[r_]);             \
    tmax_ = fmaxf(tmax_, __shfl_xor(tmax_, 32));                              \
    if (__any(tmax_ > m_run + 8.0f)) {     /* defer-max (T13), wave-uniform */\
        float mn_ = fmaxf(m_run, tmax_);                                      \
        float fr_ = exp2f(m_run - mn_);                                       \
        m_run = mn_; l_run *= fr_;                                            \
        _Pragma("unroll")                                                     \
        for (int r_ = 0; r_ < 16; ++r_) {                                     \
            O0[r_] *= fr_; O1[r_] *= fr_; O2[r_] *= fr_; O3[r_] *= fr_;       \
        }                                                                     \
    }                                                                         \
    float p_[16]; float ls_ = 0.f;                                            \
    _Pragma("unroll")                                                         \
    for (int r_ = 0; r_ < 16; ++r_) { p_[r_] = exp2f(s_[r_] - m_run); ls_ += p_[r_]; } \
    l_run += ls_;                                                             \
    /* P(f32, Sᵀ-layout) -> bf16 B-frags via cvt_pk + permlane32_swap (T12) */\
    u32 c_[8];                                                                \
    _Pragma("unroll")                                                         \
    for (int j_ = 0; j_ < 8; ++j_) {                                          \
        asm("v_cvt_pk_bf16_f32 %0, %1, %2"                                    \
            : "=v"(c_[j_]) : "v"(p_[2 * j_]), "v"(p_[2 * j_ + 1]));           \
    }                                                                         \
    asm("v_permlane32_swap_b32 %0, %1" : "+v"(c_[0]), "+v"(c_[2]));           \
    asm("v_permlane32_swap_b32 %0, %1" : "+v"(c_[1]), "+v"(c_[3]));           \
    asm("v_permlane32_swap_b32 %0, %1" : "+v"(c_[4]), "+v"(c_[6]));           \
    asm("v_permlane32_swap_b32 %0, %1" : "+v"(c_[5]), "+v"(c_[7]));           \
    bf16x8 pf0_, pf1_;                                                        \
    { u32 w_[4] = {c_[0], c_[1], c_[2], c_[3]}; __builtin_memcpy(&pf0_, w_, 16); } \
    { u32 w_[4] = {c_[4], c_[5], c_[6], c_[7]}; __builtin_memcpy(&pf1_, w_, 16); } \
    /* PV: Oᵀ[d][q] += Vᵀ·Pᵀ, d-tiles of 32, two K=16 steps (m 0-15,16-31) */ \
    O0 = __builtin_amdgcn_mfma_f32_32x32x16_bf16(vf_[0], pf0_, O0, 0, 0, 0);  \
    O1 = __builtin_amdgcn_mfma_f32_32x32x16_bf16(vf_[1], pf0_, O1, 0, 0, 0);  \
    O2 = __builtin_amdgcn_mfma_f32_32x32x16_bf16(vf_[2], pf0_, O2, 0, 0, 0);  \
    O3 = __builtin_amdgcn_mfma_f32_32x32x16_bf16(vf_[3], pf0_, O3, 0, 0, 0);  \
    O0 = __builtin_amdgcn_mfma_f32_32x32x16_bf16(vf_[4], pf1_, O0, 0, 0, 0);  \
    O1 = __builtin_amdgcn_mfma_f32_32x32x16_bf16(vf_[5], pf1_, O1, 0, 0, 0);  \
    O2 = __builtin_amdgcn_mfma_f32_32x32x16_bf16(vf_[6], pf1_, O2, 0, 0, 0);  \
    O3 = __builtin_amdgcn_mfma_f32_32x32x16_bf16(vf_[7], pf1_, O3, 0, 0, 0);  \
} while (0)

#define STORE_TILE(Ot_, dt_) do {                                             \
    _Pragma("unroll")                                                         \
    for (int g_ = 0; g_ < 4; ++g_) {                                          \
        float4 v_;                                                            \
        v_.x = Ot_[4 * g_ + 0] * rinv;                                        \
        v_.y = Ot_[4 * g_ + 1] * rinv;                                        \
        v_.z = Ot_[4 * g_ + 2] * rinv;                                        \
        v_.w = Ot_[4 * g_ + 3] * rinv;                                        \
        int d_ = (dt_) * 32 + 8 * g_ + 4 * hi32;                              \
        *(float4*)(out + (size_t)qrow * D_DIM + d_) = v_;                     \
    }                                                                         \
} while (0)

__global__ __launch_bounds__(256, 1)
void attn_main(const float* __restrict__ qin,
               const uint16_t* __restrict__ khi,
               const uint16_t* __restrict__ klo,
               const uint16_t* __restrict__ vfr,
               float* __restrict__ out) {
    const int lane = threadIdx.x & 63;
    const int wave = threadIdx.x >> 6;
    const int q0   = blockIdx.x * 128 + wave * 32;
    const int qrow = q0 + (lane & 31);
    const int hi32 = lane >> 5;

    // Q prep: load 128 f32 per q-row, scale by log2(e), split into bf16 hi/lo.
    // B-frag of Sᵀ MFMA: col=q=lane&31, k=d=(lane>>5)*8+e (+16*kk).
    bf16x8 qhi[8], qlo[8];
    {
        const float LOG2E = 1.44269504088896340736f;
        #pragma unroll
        for (int kk = 0; kk < 8; ++kk) {
            const float* src = qin + (size_t)qrow * D_DIM + kk * 16 + hi32 * 8;
            float4 a = *(const float4*)(src);
            float4 b = *(const float4*)(src + 4);
            float xs[8] = {a.x, a.y, a.z, a.w, b.x, b.y, b.z, b.w};
            #pragma unroll
            for (int e = 0; e < 8; ++e) {
                float x = xs[e] * LOG2E;
                uint16_t hb = f32_to_bf16_rne(x);
                qhi[kk][e] = (short)hb;
                qlo[kk][e] = (short)f32_to_bf16_rne(x - bf16_to_f32(hb));
            }
        }
    }

    f32x16 O0, O1, O2, O3;
    #pragma unroll
    for (int i = 0; i < 16; ++i) { O0[i] = 0.f; O1[i] = 0.f; O2[i] = 0.f; O3[i] = 0.f; }
    float m_run = -1e30f, l_run = 0.f;

    bf16x8 khA[8], klA[8], khB[8], klB[8];
    LOADK(0, khA, klA);

    for (int mt = 0; mt < MT_STEPS; mt += 2) {
        LOADK(mt + 1, khB, klB);            // prefetch next step's K frags
        STEP(mt, khA, klA);
        if (mt + 2 < MT_STEPS) LOADK(mt + 2, khA, klA);
        STEP(mt + 1, khB, klB);
    }

    // epilogue: combine pair-lane partial sums, normalize, store
    l_run += __shfl_xor(l_run, 32);
    float rinv = 1.0f / l_run;
    STORE_TILE(O0, 0);
    STORE_TILE(O1, 1);
    STORE_TILE(O2, 2);
    STORE_TILE(O3, 3);
}

extern "C" void kernel_launch(void* const* d_in, const int* in_sizes, int n_in,
                              void* d_out, int out_size, void* d_ws, size_t ws_size,
                              hipStream_t stream) {
    const float* local_stats = (const float*)d_in[0];   // [32768,128] f32
    const float* memory      = (const float*)d_in[1];   // [4096,128]  f32
    float* out = (float*)d_out;                         // [32768,128] f32

    uint16_t* khi = (uint16_t*)d_ws;        // 1 MB
    uint16_t* klo = khi + 524288;           // 1 MB
    uint16_t* vfr = klo + 524288;           // 1 MB

    prep_frags<<<256, 256, 0, stream>>>(memory, khi, klo, vfr);
    attn_main<<<256, 256, 0, stream>>>(local_stats, khi, klo, vfr, out);
}

// Round 2
// 158.143 us; speedup vs baseline: 1.9618x; 1.9618x over previous
//
#include <hip/hip_runtime.h>
#include <hip/hip_bf16.h>
#include <stdint.h>

// B=32768 queries, M=4096 memory rows, D=128.
//   logits = Q @ M^T ; attn = softmax(logits) ; out = attn @ M
// Flash-style fused kernel. bf16x3-split MFMA QK^T (near-fp32), bf16 PV.
// v2: K/V fragments staged to LDS once per block (4 waves share), 2-phase
// pipeline: QK(t+1) MFMAs issued before softmax(t) so the matrix pipe hides
// the softmax VALU chain and the LDS reads.

typedef float   f32x16 __attribute__((ext_vector_type(16)));
typedef short   bf16x8 __attribute__((ext_vector_type(8)));
typedef uint32_t u32;

#define AS1 __attribute__((address_space(1)))
#define AS3 __attribute__((address_space(3)))

#define D_DIM 128
#define MT 128            // number of 32-row memory tiles
#define TILE_HW 12288     // halfwords per tile in kv ws: [khi 4096|klo 4096|v 4096]

#if __has_builtin(__builtin_amdgcn_exp2f)
#define EXP2F(x) __builtin_amdgcn_exp2f(x)
#else
#define EXP2F(x) exp2f(x)
#endif

__device__ __forceinline__ uint16_t f32_to_bf16_rne(float x) {
    u32 u = __float_as_uint(x);
    u32 r = u + 0x7fffu + ((u >> 16) & 1u);
    return (uint16_t)(r >> 16);
}
__device__ __forceinline__ float bf16_to_f32(uint16_t h) {
    return __uint_as_float(((u32)h) << 16);
}

// ---------------------------------------------------------------------------
// Prep: memory -> interleaved fragment-linear bf16 tiles in d_ws.
// Per tile mt (24576 B): [0,8K) khi frags, [8K,16K) klo frags, [16K,24K) v frags.
//   khi/klo frag kk: element = memory[mt*32 + (lane&31)][kk*16 + (lane>>5)*8 + e]
//   v frag f=ks*4+dt: element = memory[mt*32 + ks*16 + (lane>>5)*8 + e][dt*32 + (lane&31)]
// ---------------------------------------------------------------------------
__global__ void prep_frags(const float* __restrict__ mem,
                           uint16_t* __restrict__ kv) {
    int t = blockIdx.x * blockDim.x + threadIdx.x;  // 0..65535
    int lane = t & 63;
    int fi = t >> 6;                                // 0..1023
    int f8 = fi & 7, mt = fi >> 3;
    size_t base = (size_t)mt * TILE_HW;
    {   // K fragment (hi/lo split)
        int m  = mt * 32 + (lane & 31);
        int d0 = f8 * 16 + (lane >> 5) * 8;
        const float* src = mem + (size_t)m * D_DIM + d0;
        #pragma unroll
        for (int e = 0; e < 8; ++e) {
            float x = src[e];
            uint16_t hb = f32_to_bf16_rne(x);
            kv[base + f8 * 512 + lane * 8 + e] = hb;
            kv[base + 4096 + f8 * 512 + lane * 8 + e] =
                f32_to_bf16_rne(x - bf16_to_f32(hb));
        }
    }
    {   // V^T fragment (plain bf16)
        int dt = fi & 3, ks = (fi >> 2) & 1;
        int d  = dt * 32 + (lane & 31);
        int m0 = mt * 32 + ks * 16 + (lane >> 5) * 8;
        #pragma unroll
        for (int e = 0; e < 8; ++e)
            kv[base + 8192 + f8 * 512 + lane * 8 + e] =
                f32_to_bf16_rne(mem[(size_t)(m0 + e) * D_DIM + d]);
    }
}

// ---------------------------------------------------------------------------
// Main kernel: 256 blocks x 256 threads (4 waves). Each wave: 32 q-rows.
// LDS: double-buffered 24KB tiles. 1 wave/SIMD by construction.
// ---------------------------------------------------------------------------

#define STAGE(tile_, wb_) do {                                                \
    const char* g_ = (const char*)(kv + (size_t)(tile_) * TILE_HW);           \
    char* l_ = (char*)&sbuf[wb_][0];                                          \
    _Pragma("unroll")                                                         \
    for (int j_ = 0; j_ < 6; ++j_) {                                          \
        int ch_ = wave * 6 + j_;                                              \
        __builtin_amdgcn_global_load_lds(                                     \
            (const AS1 char*)(g_ + ch_ * 1024 + lane * 16),                   \
            (AS3 char*)(l_ + ch_ * 1024), 16, 0, 0);                          \
    }                                                                         \
} while (0)

#define READ_KV(rb_, vf_) do {                                                \
    const uint16_t* b_ = &sbuf[rb_][0] + lane * 8;                            \
    _Pragma("unroll")                                                         \
    for (int kk_ = 0; kk_ < 8; ++kk_) {                                       \
        kh[kk_]  = *(const bf16x8*)(b_ + kk_ * 512);                          \
        kl[kk_]  = *(const bf16x8*)(b_ + 4096 + kk_ * 512);                   \
        vf_[kk_] = *(const bf16x8*)(b_ + 8192 + kk_ * 512);                   \
    }                                                                         \
} while (0)

// Declares s0_,s1_,s2_ in enclosing scope; issues 24 MFMAs for tile's QK^T.
#define QK_ISSUE()                                                            \
    f32x16 s0_, s1_, s2_;                                                     \
    _Pragma("unroll")                                                         \
    for (int i_ = 0; i_ < 16; ++i_) { s0_[i_]=0.f; s1_[i_]=0.f; s2_[i_]=0.f; }\
    _Pragma("unroll")                                                         \
    for (int kk_ = 0; kk_ < 8; ++kk_) {                                       \
        s0_ = __builtin_amdgcn_mfma_f32_32x32x16_bf16(kh[kk_], qhi[kk_], s0_, 0, 0, 0); \
        s1_ = __builtin_amdgcn_mfma_f32_32x32x16_bf16(kh[kk_], qlo[kk_], s1_, 0, 0, 0); \
        s2_ = __builtin_amdgcn_mfma_f32_32x32x16_bf16(kl[kk_], qhi[kk_], s2_, 0, 0, 0); \
    }

// Online softmax on sC_ (summed log2-logits, Sᵀ layout: q=lane&31) + PV MFMAs.
#define SOFTMAX_PV(sC_, vfC_) do {                                            \
    float a0_=fmaxf(sC_[0],sC_[1]),  a1_=fmaxf(sC_[2],sC_[3]);                \
    float a2_=fmaxf(sC_[4],sC_[5]),  a3_=fmaxf(sC_[6],sC_[7]);                \
    float a4_=fmaxf(sC_[8],sC_[9]),  a5_=fmaxf(sC_[10],sC_[11]);              \
    float a6_=fmaxf(sC_[12],sC_[13]),a7_=fmaxf(sC_[14],sC_[15]);              \
    float b0_=fmaxf(a0_,a1_), b1_=fmaxf(a2_,a3_);                             \
    float b2_=fmaxf(a4_,a5_), b3_=fmaxf(a6_,a7_);                             \
    float tmax_ = fmaxf(fmaxf(b0_,b1_), fmaxf(b2_,b3_));                      \
    tmax_ = fmaxf(tmax_, __shfl_xor(tmax_, 32));                              \
    if (__any(tmax_ > m_run + 8.0f)) {     /* defer-max (T13) */              \
        float mn_ = fmaxf(m_run, tmax_);                                      \
        float fr_ = EXP2F(m_run - mn_);                                       \
        m_run = mn_; l_run *= fr_;                                            \
        _Pragma("unroll")                                                     \
        for (int r_ = 0; r_ < 16; ++r_) {                                     \
            O0[r_] *= fr_; O1[r_] *= fr_; O2[r_] *= fr_; O3[r_] *= fr_;       \
        }                                                                     \
    }                                                                         \
    float p_[16];                                                             \
    _Pragma("unroll")                                                         \
    for (int r_ = 0; r_ < 16; ++r_) p_[r_] = EXP2F(sC_[r_] - m_run);          \
    { float q0_=p_[0]+p_[1],  q1_=p_[2]+p_[3],  q2_=p_[4]+p_[5],  q3_=p_[6]+p_[7];   \
      float q4_=p_[8]+p_[9],  q5_=p_[10]+p_[11],q6_=p_[12]+p_[13],q7_=p_[14]+p_[15]; \
      l_run += ((q0_+q1_)+(q2_+q3_)) + ((q4_+q5_)+(q6_+q7_)); }               \
    u32 c_[8];                                                                \
    _Pragma("unroll")                                                         \
    for (int j_ = 0; j_ < 8; ++j_)                                            \
        asm("v_cvt_pk_bf16_f32 %0, %1, %2"                                    \
            : "=v"(c_[j_]) : "v"(p_[2*j_]), "v"(p_[2*j_+1]));                 \
    asm("v_permlane32_swap_b32 %0, %1" : "+v"(c_[0]), "+v"(c_[2]));           \
    asm("v_permlane32_swap_b32 %0, %1" : "+v"(c_[1]), "+v"(c_[3]));           \
    asm("v_permlane32_swap_b32 %0, %1" : "+v"(c_[4]), "+v"(c_[6]));           \
    asm("v_permlane32_swap_b32 %0, %1" : "+v"(c_[5]), "+v"(c_[7]));           \
    bf16x8 pf0_, pf1_;                                                        \
    { u32 w_[4] = {c_[0], c_[1], c_[2], c_[3]}; __builtin_memcpy(&pf0_, w_, 16); } \
    { u32 w_[4] = {c_[4], c_[5], c_[6], c_[7]}; __builtin_memcpy(&pf1_, w_, 16); } \
    O0 = __builtin_amdgcn_mfma_f32_32x32x16_bf16(vfC_[0], pf0_, O0, 0, 0, 0); \
    O1 = __builtin_amdgcn_mfma_f32_32x32x16_bf16(vfC_[1], pf0_, O1, 0, 0, 0); \
    O2 = __builtin_amdgcn_mfma_f32_32x32x16_bf16(vfC_[2], pf0_, O2, 0, 0, 0); \
    O3 = __builtin_amdgcn_mfma_f32_32x32x16_bf16(vfC_[3], pf0_, O3, 0, 0, 0); \
    O0 = __builtin_amdgcn_mfma_f32_32x32x16_bf16(vfC_[4], pf1_, O0, 0, 0, 0); \
    O1 = __builtin_amdgcn_mfma_f32_32x32x16_bf16(vfC_[5], pf1_, O1, 0, 0, 0); \
    O2 = __builtin_amdgcn_mfma_f32_32x32x16_bf16(vfC_[6], pf1_, O2, 0, 0, 0); \
    O3 = __builtin_amdgcn_mfma_f32_32x32x16_bf16(vfC_[7], pf1_, O3, 0, 0, 0); \
} while (0)

// One pipeline stage: read tile tn_ frags, stage tile tn_+1, issue QK(tn_)
// (fills MFMA pipe), softmax+PV of tile tn_-1 (VALU overlaps), sum scores.
#define HALF(tn_, rb_, sCur_, sNxt_, vfCur_, vfNxt_, doStage_) do {           \
    READ_KV(rb_, vfNxt_);                                                     \
    if (doStage_) STAGE((tn_) + 1, (rb_) ^ 1);                                \
    QK_ISSUE();                                                               \
    SOFTMAX_PV(sCur_, vfCur_);                                                \
    sNxt_ = s0_ + s1_ + s2_;                                                  \
    __syncthreads();                                                          \
} while (0)

#define STORE_TILE(Ot_, dt_) do {                                             \
    _Pragma("unroll")                                                         \
    for (int g_ = 0; g_ < 4; ++g_) {                                          \
        float4 v_;                                                            \
        v_.x = Ot_[4*g_+0] * rinv;                                            \
        v_.y = Ot_[4*g_+1] * rinv;                                            \
        v_.z = Ot_[4*g_+2] * rinv;                                            \
        v_.w = Ot_[4*g_+3] * rinv;                                            \
        int d_ = (dt_) * 32 + 8 * g_ + 4 * hi32;                              \
        *(float4*)(out + (size_t)qrow * D_DIM + d_) = v_;                     \
    }                                                                         \
} while (0)

__global__ __launch_bounds__(256, 1)
void attn_main(const float* __restrict__ qin,
               const uint16_t* __restrict__ kv,
               float* __restrict__ out) {
    __shared__ uint16_t sbuf[2][TILE_HW];   // 2 x 24 KB

    const int lane = threadIdx.x & 63;
    const int wave = threadIdx.x >> 6;
    const int q0   = blockIdx.x * 128 + wave * 32;
    const int qrow = q0 + (lane & 31);
    const int hi32 = lane >> 5;

    // Q prep: scale by log2(e), split into bf16 hi/lo (B-frag of Sᵀ MFMA).
    bf16x8 qhi[8], qlo[8];
    {
        const float LOG2E = 1.44269504088896340736f;
        #pragma unroll
        for (int kk = 0; kk < 8; ++kk) {
            const float* src = qin + (size_t)qrow * D_DIM + kk * 16 + hi32 * 8;
            float4 a = *(const float4*)(src);
            float4 b = *(const float4*)(src + 4);
            float xs[8] = {a.x, a.y, a.z, a.w, b.x, b.y, b.z, b.w};
            #pragma unroll
            for (int e = 0; e < 8; ++e) {
                float x = xs[e] * LOG2E;
                uint16_t hb = f32_to_bf16_rne(x);
                qhi[kk][e] = (short)hb;
                qlo[kk][e] = (short)f32_to_bf16_rne(x - bf16_to_f32(hb));
            }
        }
    }

    f32x16 O0, O1, O2, O3;
    #pragma unroll
    for (int i = 0; i < 16; ++i) { O0[i]=0.f; O1[i]=0.f; O2[i]=0.f; O3[i]=0.f; }
    float m_run = -1e30f, l_run = 0.f;

    bf16x8 kh[8], kl[8], vfA[8], vfB[8];
    f32x16 sA, sB;

    // Pipeline prologue: stage(0), QK(0) -> sA, stage(1).
    STAGE(0, 0);
    __syncthreads();
    READ_KV(0, vfA);
    STAGE(1, 1);
    {
        QK_ISSUE();
        sA = s0_ + s1_ + s2_;
    }
    __syncthreads();

    // Steady state: halves tn = 1..126 in pairs, then tn = 127 (no stage).
    #pragma unroll 1
    for (int tp = 0; tp < 63; ++tp) {
        const int tn = 2 * tp + 1;
        HALF(tn,     1, sA, sB, vfA, vfB, true);
        HALF(tn + 1, 0, sB, sA, vfB, vfA, true);
    }
    HALF(127, 1, sA, sB, vfA, vfB, false);
    // Drain: softmax + PV for tile 127.
    SOFTMAX_PV(sB, vfB);

    // Epilogue: combine pair-lane partial sums, normalize, store.
    l_run += __shfl_xor(l_run, 32);
    float rinv = 1.0f / l_run;
    STORE_TILE(O0, 0);
    STORE_TILE(O1, 1);
    STORE_TILE(O2, 2);
    STORE_TILE(O3, 3);
}

extern "C" void kernel_launch(void* const* d_in, const int* in_sizes, int n_in,
                              void* d_out, int out_size, void* d_ws, size_t ws_size,
                              hipStream_t stream) {
    const float* local_stats = (const float*)d_in[0];   // [32768,128] f32
    const float* memory      = (const float*)d_in[1];   // [4096,128]  f32
    float* out = (float*)d_out;                         // [32768,128] f32

    uint16_t* kv = (uint16_t*)d_ws;   // 128 tiles x 24576 B = 3 MB

    prep_frags<<<256, 256, 0, stream>>>(memory, kv);
    attn_main<<<256, 256, 0, stream>>>(local_stats, kv, out);
}